// Round 7
// baseline (6128.880 us; speedup 1.0000x reference)
//
#include <hip/hip_runtime.h>
#include <hip/hip_bf16.h>

// CharNNClassifier: out = (LSTM(emb[x]) last h) @ W_out^T + b_out
// B=256 S=512 V=256 E=128 H=256 4H=1024 O=128, fp32 in/out.
//
// R7 = R6 with __launch_bounds__(512, 1).
// KEY LESSON (R2-R6): HIP __launch_bounds__ 2nd arg acts like CUDA's
// minBlocksPerMultiprocessor. (512,2) => 2 blocks/CU => 128-VGPR cap =>
// the 128-reg wfrag spilled wholesale to scratch (R6: VGPR_Count=52,
// WRITE_SIZE=74MB of scratch traffic). (512,1) => 256-VGPR budget; live
// state ~225 regs fits.
//
// Design recap:
//  - 32 wgs x 512 threads = 16 stripe-pairs. Block q of pair p owns hidden
//    units [q*128, +128) for batch rows [p*16, +16): 4 n-tiles x 8 kt
//    B-frags = 128 VGPRs -> this wg's W_hh slice fully register-resident.
//  - Per step: own h-half via LDS; partner h-half (4 KB) via relaxed
//    AGENT-scope u64 atomic loads (IF-coherent, XCD-safe), guarded by
//    monotonic release/acquire prog flags. Remote loads issue before the
//    local-half MFMAs so IF latency partially hides under compute.
//  - c fp32 in regs; h rounded to fp16 once per step.
//
// hx layout: u64 hx[ block(=pair*2+q) ][ parity ][ row 0..15 ][ ugrp 0..31 ]
// Flag protocol (monotonic, per block): flag = s+1 released after h_s stored.
// Step-s consumer acquires partner flag >= s. Parity-buffer overwrite at
// step s is fenced by the same flag (partner's release orders its reads of
// h_{s-2} before flag=s became visible).

typedef _Float16 f16x8 __attribute__((ext_vector_type(8)));
typedef _Float16 f16x4 __attribute__((ext_vector_type(4)));
typedef float    f32x4 __attribute__((ext_vector_type(4)));

#define B_  256
#define S_  512
#define V_  256
#define E_  128
#define H_  256
#define O_  128
#define NPAIR 16

// ws layout (bytes)
#define T_OFF     0u              // T2h: 256*256*4 fp16 = 512 KiB
#define HLAST_OFF (1u << 19)      // hlast: 256 KiB
#define HX_OFF    (HLAST_OFF + (1u << 18))   // hx: 32 blocks*2*16*32 u64 = 256 KiB
#define PROG_OFF  (HX_OFF + (1u << 18))      // prog: 32 ints

// ---------------------------------------------------------------- K1: table
// T2h[v][unit] = fp16x4 {i,f,g,o} pre-activations from the embedding path.
__global__ void build_table(const float* __restrict__ emb,
                            const float* __restrict__ W_ih,
                            const float* __restrict__ b_ih,
                            const float* __restrict__ b_hh,
                            _Float16* __restrict__ T2h,
                            int* __restrict__ prog) {
    const int v   = blockIdx.x;   // vocab id
    const int tid = threadIdx.x;  // 256 threads = hidden unit

    if (v == 0 && tid < 2 * NPAIR) prog[tid] = 0;   // re-init flags per launch

    __shared__ float e[E_];
    if (tid < E_) e[tid] = emb[v * E_ + tid];
    __syncthreads();

    f16x4 tv;
#pragma unroll
    for (int t = 0; t < 4; ++t) {
        const int g = t * 256 + tid;
        const float4* wp = (const float4*)(W_ih + g * E_);
        float acc = 0.f;
#pragma unroll
        for (int i = 0; i < E_ / 4; ++i) {
            float4 w = wp[i];
            acc += w.x * e[4*i] + w.y * e[4*i+1] + w.z * e[4*i+2] + w.w * e[4*i+3];
        }
        tv[t] = (_Float16)(acc + b_ih[g] + b_hh[g]);
    }
    *(f16x4*)(T2h + ((size_t)v * 256 + tid) * 4) = tv;
}

// ------------------------------------------------------------ K2: recurrence
// clamp-free: x<<0 -> t=inf -> rcp(inf)=0 ; x>>0 -> t=0 -> 1.  NaN-free.
__device__ __forceinline__ float sig_fast(float x) {
    float t = __builtin_amdgcn_exp2f(-1.4426950408889634f * x);
    return __builtin_amdgcn_rcpf(1.f + t);
}
// abs-form: exp2 arg <= 0 -> never overflows; copysign restores sign.
__device__ __forceinline__ float tanh_fast(float x) {
    float ax = fabsf(x);
    float t  = __builtin_amdgcn_exp2f(-2.8853900817779268f * ax);  // e^{-2|x|}
    float y  = (1.f - t) * __builtin_amdgcn_rcpf(1.f + t);
    return copysignf(y, x);
}

#define HSTRIDE 136   // fp16 per LDS h row (128 + 8 pad)

__launch_bounds__(512, 1)   // 1 block/CU => 256-VGPR budget (THE R7 fix)
__global__ void lstm_persistent(const int* __restrict__ x,
                                const float* __restrict__ W_hh,
                                const _Float16* __restrict__ T2h,
                                unsigned long long* __restrict__ hx,
                                int* __restrict__ prog,
                                float* __restrict__ hlast) {
    const int tid  = threadIdx.x;
    const int wv   = tid >> 6;       // wave 0..7
    const int l    = tid & 63;
    const int l15  = l & 15;
    const int quad = l >> 4;         // 0..3
    const int pair = blockIdx.x >> 1;    // batch stripe 0..15
    const int q    = blockIdx.x & 1;     // hidden half 0..1

    // ---- prologue: this wg's W_hh quarter -> fp16 B-frags, ALL in regs.
    // Wave wv owns local units [wv*16, +16); gate col for tile t:
    // n = t*256 + q*128 + wv*16 + l15.  B[k][n] = W_hh[n][k],
    // lane k-offset = kt*32 + quad*8 (full k range 0..255 in regs).
    f16x8 wfrag[4][8];
#pragma unroll
    for (int t = 0; t < 4; ++t) {
        const float* wr =
            W_hh + (size_t)(t * 256 + q * 128 + wv * 16 + l15) * H_ + quad * 8;
#pragma unroll
        for (int kt = 0; kt < 8; ++kt) {
            const float4* wp = (const float4*)(wr + kt * 32);
            float4 w0 = wp[0];
            float4 w1 = wp[1];
            wfrag[t][kt] = (f16x8){
                (_Float16)w0.x, (_Float16)w0.y, (_Float16)w0.z, (_Float16)w0.w,
                (_Float16)w1.x, (_Float16)w1.y, (_Float16)w1.z, (_Float16)w1.w};
        }
    }

    // own h-half double buffer (16 rows x 128 local units)
    __shared__ __align__(16) _Float16 hbuf[2][16][HSTRIDE];

    int* my_flag = prog + pair * 2 + q;
    const int* partner_flag = prog + pair * 2 + (1 - q);
    const int self_blk = pair * 2 + q;
    const int rem_blk  = pair * 2 + (1 - q);

    const int row0  = pair * 16 + quad * 4;  // this lane's 4 C-rows (global)
    const int u_loc = wv * 16 + l15;         // local unit 0..127
    const int u_gl  = q * 128 + u_loc;       // global unit
    // local MFMA k-tiles: kt in [4q, 4q+4); remote: the other 4.
    const int kt_loc0 = 4 * q;
    const int kt_rem0 = 4 * (1 - q);

    float c[4] = {0.f, 0.f, 0.f, 0.f};

    for (int s = 0; s < S_; ++s) {
        // x indices for this lane's 4 rows (L1-resident)
        int vv[4];
#pragma unroll
        for (int r = 0; r < 4; ++r) vv[r] = x[(row0 + r) * S_ + s];
        // prefetch gate-table rows (L2) — independent of h
        f16x4 tv[4];
#pragma unroll
        for (int r = 0; r < 4; ++r)
            tv[r] = *(const f16x4*)(T2h + ((size_t)vv[r] * 256 + u_gl) * 4);

        f32x4 acc[4];
#pragma unroll
        for (int t = 0; t < 4; ++t) acc[t] = (f32x4){0.f, 0.f, 0.f, 0.f};

        if (s > 0) {
            const int par = (s - 1) & 1;
            // local A-frags from LDS (k_local = kr*32 + quad*8)
            const _Float16* hb = &hbuf[par][0][0] + l15 * HSTRIDE + quad * 8;
            f16x8 a_loc[4];
#pragma unroll
            for (int kr = 0; kr < 4; ++kr)
                a_loc[kr] = *(const f16x8*)(hb + kr * 32);

            // wait for partner's h_{s-1}, then pull remote half (8 u64/lane)
            while (__hip_atomic_load(partner_flag, __ATOMIC_ACQUIRE,
                                     __HIP_MEMORY_SCOPE_AGENT) < s) { }
            // remote base: same formula as the write side, partner block
            const unsigned long long* rb =
                hx + ((size_t)(rem_blk * 2 + par) * 16) * 32;
            f16x8 a_rem[4];
#pragma unroll
            for (int kr = 0; kr < 4; ++kr) {
                // A[m=l15][k_rem_local = kr*32 + quad*8 + i] -> row l15,
                // u64 groups kr*8 + quad*2, +1
                const size_t idx = (size_t)l15 * 32 + kr * 8 + quad * 2;
                union { unsigned long long u[2]; f16x8 v; } cv;
                cv.u[0] = __hip_atomic_load(rb + idx, __ATOMIC_RELAXED,
                                            __HIP_MEMORY_SCOPE_AGENT);
                cv.u[1] = __hip_atomic_load(rb + idx + 1, __ATOMIC_RELAXED,
                                            __HIP_MEMORY_SCOPE_AGENT);
                a_rem[kr] = cv.v;
            }
            // local-half MFMAs first (remote loads in flight above them)
#pragma unroll
            for (int kr = 0; kr < 4; ++kr)
#pragma unroll
                for (int t = 0; t < 4; ++t)
                    acc[t] = __builtin_amdgcn_mfma_f32_16x16x32_f16(
                        a_loc[kr], wfrag[t][kt_loc0 + kr], acc[t], 0, 0, 0);
#pragma unroll
            for (int kr = 0; kr < 4; ++kr)
#pragma unroll
                for (int t = 0; t < 4; ++t)
                    acc[t] = __builtin_amdgcn_mfma_f32_16x16x32_f16(
                        a_rem[kr], wfrag[t][kt_rem0 + kr], acc[t], 0, 0, 0);
        }

        // epilogue: 4 h-values per lane (rows quad*4+r, unit u_loc).
        // C/D layout: col = l15, row = quad*4 + r.
#pragma unroll
        for (int r = 0; r < 4; ++r) {
            float gi = sig_fast (acc[0][r] + (float)tv[r][0]);
            float gf = sig_fast (acc[1][r] + (float)tv[r][1]);
            float gg = tanh_fast(acc[2][r] + (float)tv[r][2]);
            float go = sig_fast (acc[3][r] + (float)tv[r][3]);
            float cc = gf * c[r] + gi * gg;
            c[r] = cc;
            float hv = go * tanh_fast(cc);
            if (s < S_ - 1)
                hbuf[s & 1][quad * 4 + r][u_loc] = (_Float16)hv;
            else
                hlast[(row0 + r) * H_ + u_gl] = hv;   // fp32 for the head
        }

        if (s < S_ - 1) {
            __syncthreads();   // own half complete in LDS
            // repack own half -> global hx (one u64 per thread, coalesced)
            {
                const int row  = tid >> 5;        // 0..15
                const int ugrp = tid & 31;        // 0..31 (4 fp16 each)
                unsigned long long pk = *(const unsigned long long*)
                    (&hbuf[s & 1][row][ugrp * 4]);
                const size_t didx =
                    ((size_t)(self_blk * 2 + (s & 1)) * 16 + row) * 32 + ugrp;
                __hip_atomic_store(hx + didx, pk, __ATOMIC_RELAXED,
                                   __HIP_MEMORY_SCOPE_AGENT);
            }
            __syncthreads();   // all 512 stores issued before flag publish
            if (tid == 0)
                __hip_atomic_store(my_flag, s + 1, __ATOMIC_RELEASE,
                                   __HIP_MEMORY_SCOPE_AGENT);
        }
    }
}

// ---------------------------------------------------------------- K3: head
__global__ void out_kernel(const float* __restrict__ hlast,
                           const float* __restrict__ W_out,
                           const float* __restrict__ b_out,
                           float* __restrict__ out) {
    const int b = blockIdx.x;    // 256
    const int o = threadIdx.x;   // 128
    __shared__ float hl[H_];
    hl[o]       = hlast[b * H_ + o];
    hl[o + 128] = hlast[b * H_ + o + 128];
    __syncthreads();
    const float4* wp = (const float4*)(W_out + o * H_);
    float acc = 0.f;
#pragma unroll
    for (int i = 0; i < H_ / 4; ++i) {
        float4 w = wp[i];
        acc += w.x * hl[4*i] + w.y * hl[4*i+1] + w.z * hl[4*i+2] + w.w * hl[4*i+3];
    }
    out[b * O_ + o] = acc + b_out[o];
}

// ----------------------------------------------------------------- launcher
extern "C" void kernel_launch(void* const* d_in, const int* in_sizes, int n_in,
                              void* d_out, int out_size, void* d_ws, size_t ws_size,
                              hipStream_t stream) {
    const int*   x     = (const int*)  d_in[0];
    const float* emb   = (const float*)d_in[1];
    const float* W_ih  = (const float*)d_in[2];
    const float* W_hh  = (const float*)d_in[3];
    const float* b_ih  = (const float*)d_in[4];
    const float* b_hh  = (const float*)d_in[5];
    const float* W_out = (const float*)d_in[6];
    const float* b_out = (const float*)d_in[7];
    float* out = (float*)d_out;

    char* ws = (char*)d_ws;
    _Float16*           T2h   = (_Float16*)(ws + T_OFF);
    float*              hlast = (float*)(ws + HLAST_OFF);
    unsigned long long* hx    = (unsigned long long*)(ws + HX_OFF);
    int*                prog  = (int*)(ws + PROG_OFF);

    build_table<<<dim3(V_), dim3(256), 0, stream>>>(emb, W_ih, b_ih, b_hh, T2h, prog);
    lstm_persistent<<<dim3(2 * NPAIR), dim3(512), 0, stream>>>(
        x, W_hh, T2h, hx, prog, hlast);
    out_kernel<<<dim3(B_), dim3(O_), 0, stream>>>(hlast, W_out, b_out, out);
}

// Round 8
// 3029.275 us; speedup vs baseline: 2.0232x; 2.0232x over previous
//
#include <hip/hip_runtime.h>
#include <hip/hip_bf16.h>

// CharNNClassifier: out = (LSTM(emb[x]) last h) @ W_out^T + b_out
// B=256 S=512 V=256 E=128 H=256 4H=1024 O=128, fp32 in/out.
//
// R8 = R7 with wfrag indexing made COMPILE-TIME CONSTANT.
// KEY LESSON (R5-R7): `wfrag[t][kt_loc0 + kr]` with kt_loc0 = 4*q (runtime,
// from blockIdx) defeats SROA -> the whole per-thread array demotes to
// scratch -> VGPR_Count=52, WRITE_SIZE=74MB, MFMA B-operands streamed from
// scratch every step. launch_bounds was irrelevant (R7 proved it).
// Fix: store B-frags in LOGICAL slot order (slot 0..3 = my k-tiles,
// slot 4..7 = partner's k-tiles); runtime q only affects prologue ADDRESSES.
//
// Design recap:
//  - 32 wgs x 512 threads = 16 stripe-pairs. Block q of pair p owns hidden
//    units [q*128, +128) for batch rows [p*16, +16): 4 n-tiles x 8 k-slots
//    of B-frags = 128 VGPRs, fully register-resident.
//  - Per step: own h-half via LDS; partner h-half (4 KB) via relaxed
//    AGENT-scope u64 atomic loads (IF-coherent, XCD-safe), guarded by
//    monotonic release/acquire prog flags. Remote loads issue before the
//    local-half MFMAs so IF latency partially hides under compute.
//  - c fp32 in regs; h rounded to fp16 once per step.
//
// hx layout: u64 hx[ block(=pair*2+q) ][ parity ][ row 0..15 ][ ugrp 0..31 ]
// Flag protocol (monotonic, per block): flag = s+1 released after h_s stored.
// Step-s consumer acquires partner flag >= s. Parity-buffer overwrite at
// step s is fenced by the same flag (partner's release orders its reads of
// h_{s-2} before flag=s became visible).

typedef _Float16 f16x8 __attribute__((ext_vector_type(8)));
typedef _Float16 f16x4 __attribute__((ext_vector_type(4)));
typedef float    f32x4 __attribute__((ext_vector_type(4)));

#define B_  256
#define S_  512
#define V_  256
#define E_  128
#define H_  256
#define O_  128
#define NPAIR 16

// ws layout (bytes)
#define T_OFF     0u              // T2h: 256*256*4 fp16 = 512 KiB
#define HLAST_OFF (1u << 19)      // hlast: 256 KiB
#define HX_OFF    (HLAST_OFF + (1u << 18))   // hx: 32 blocks*2*16*32 u64 = 256 KiB
#define PROG_OFF  (HX_OFF + (1u << 18))      // prog: 32 ints

// ---------------------------------------------------------------- K1: table
// T2h[v][unit] = fp16x4 {i,f,g,o} pre-activations from the embedding path.
__global__ void build_table(const float* __restrict__ emb,
                            const float* __restrict__ W_ih,
                            const float* __restrict__ b_ih,
                            const float* __restrict__ b_hh,
                            _Float16* __restrict__ T2h,
                            int* __restrict__ prog) {
    const int v   = blockIdx.x;   // vocab id
    const int tid = threadIdx.x;  // 256 threads = hidden unit

    if (v == 0 && tid < 2 * NPAIR) prog[tid] = 0;   // re-init flags per launch

    __shared__ float e[E_];
    if (tid < E_) e[tid] = emb[v * E_ + tid];
    __syncthreads();

    f16x4 tv;
#pragma unroll
    for (int t = 0; t < 4; ++t) {
        const int g = t * 256 + tid;
        const float4* wp = (const float4*)(W_ih + g * E_);
        float acc = 0.f;
#pragma unroll
        for (int i = 0; i < E_ / 4; ++i) {
            float4 w = wp[i];
            acc += w.x * e[4*i] + w.y * e[4*i+1] + w.z * e[4*i+2] + w.w * e[4*i+3];
        }
        tv[t] = (_Float16)(acc + b_ih[g] + b_hh[g]);
    }
    *(f16x4*)(T2h + ((size_t)v * 256 + tid) * 4) = tv;
}

// ------------------------------------------------------------ K2: recurrence
// clamp-free: x<<0 -> t=inf -> rcp(inf)=0 ; x>>0 -> t=0 -> 1.  NaN-free.
__device__ __forceinline__ float sig_fast(float x) {
    float t = __builtin_amdgcn_exp2f(-1.4426950408889634f * x);
    return __builtin_amdgcn_rcpf(1.f + t);
}
// abs-form: exp2 arg <= 0 -> never overflows; copysign restores sign.
__device__ __forceinline__ float tanh_fast(float x) {
    float ax = fabsf(x);
    float t  = __builtin_amdgcn_exp2f(-2.8853900817779268f * ax);  // e^{-2|x|}
    float y  = (1.f - t) * __builtin_amdgcn_rcpf(1.f + t);
    return copysignf(y, x);
}

#define HSTRIDE 136   // fp16 per LDS h row (128 + 8 pad)

__launch_bounds__(512, 1)
__global__ void lstm_persistent(const int* __restrict__ x,
                                const float* __restrict__ W_hh,
                                const _Float16* __restrict__ T2h,
                                unsigned long long* __restrict__ hx,
                                int* __restrict__ prog,
                                float* __restrict__ hlast) {
    const int tid  = threadIdx.x;
    const int wv   = tid >> 6;       // wave 0..7
    const int l    = tid & 63;
    const int l15  = l & 15;
    const int quad = l >> 4;         // 0..3
    const int pair = blockIdx.x >> 1;    // batch stripe 0..15
    const int q    = blockIdx.x & 1;     // hidden half 0..1

    // ---- prologue: W_hh slice -> fp16 B-frags in LOGICAL slot order.
    // slot 0..3  = my own k-tiles   (k_global = q*128     + slot*32)
    // slot 4..7  = partner k-tiles  (k_global = (1-q)*128 + (slot-4)*32)
    // Gate col for n-tile t: n = t*256 + q*128 + wv*16 + l15.
    // B[k][n] = W_hh[n][k]; lane k-offset inside a tile = quad*8 + i.
    // ALL wfrag accesses are compile-time indexed => SROA promotes to regs.
    f16x8 wfrag[4][8];
#pragma unroll
    for (int t = 0; t < 4; ++t) {
        const float* wr =
            W_hh + (size_t)(t * 256 + q * 128 + wv * 16 + l15) * H_ + quad * 8;
#pragma unroll
        for (int slot = 0; slot < 8; ++slot) {
            const int k0 = (slot < 4) ? (q * 128 + slot * 32)
                                      : ((1 - q) * 128 + (slot - 4) * 32);
            const float4* wp = (const float4*)(wr + k0);
            float4 w0 = wp[0];
            float4 w1 = wp[1];
            wfrag[t][slot] = (f16x8){
                (_Float16)w0.x, (_Float16)w0.y, (_Float16)w0.z, (_Float16)w0.w,
                (_Float16)w1.x, (_Float16)w1.y, (_Float16)w1.z, (_Float16)w1.w};
        }
    }

    // own h-half double buffer (16 rows x 128 local units)
    __shared__ __align__(16) _Float16 hbuf[2][16][HSTRIDE];

    int* my_flag = prog + pair * 2 + q;
    const int* partner_flag = prog + pair * 2 + (1 - q);
    const int self_blk = pair * 2 + q;
    const int rem_blk  = pair * 2 + (1 - q);

    const int row0  = pair * 16 + quad * 4;  // this lane's 4 C-rows (global)
    const int u_loc = wv * 16 + l15;         // local unit 0..127
    const int u_gl  = q * 128 + u_loc;       // global unit

    float c[4] = {0.f, 0.f, 0.f, 0.f};

    for (int s = 0; s < S_; ++s) {
        // x indices for this lane's 4 rows (L1-resident)
        int vv[4];
#pragma unroll
        for (int r = 0; r < 4; ++r) vv[r] = x[(row0 + r) * S_ + s];
        // prefetch gate-table rows (L2) — independent of h
        f16x4 tv[4];
#pragma unroll
        for (int r = 0; r < 4; ++r)
            tv[r] = *(const f16x4*)(T2h + ((size_t)vv[r] * 256 + u_gl) * 4);

        f32x4 acc[4];
#pragma unroll
        for (int t = 0; t < 4; ++t) acc[t] = (f32x4){0.f, 0.f, 0.f, 0.f};

        if (s > 0) {
            const int par = (s - 1) & 1;
            // local A-frags from LDS: A[m=l15][k_local = kr*32 + quad*8 + i]
            const _Float16* hb = &hbuf[par][0][0] + l15 * HSTRIDE + quad * 8;
            f16x8 a_loc[4];
#pragma unroll
            for (int kr = 0; kr < 4; ++kr)
                a_loc[kr] = *(const f16x8*)(hb + kr * 32);

            // wait for partner's h_{s-1}, then pull remote half (8 u64/lane)
            while (__hip_atomic_load(partner_flag, __ATOMIC_ACQUIRE,
                                     __HIP_MEMORY_SCOPE_AGENT) < s) { }
            const unsigned long long* rb =
                hx + ((size_t)(rem_blk * 2 + par) * 16) * 32;
            f16x8 a_rem[4];
#pragma unroll
            for (int kr = 0; kr < 4; ++kr) {
                // A[m=l15][k_partner_local = kr*32 + quad*8 + i]
                const size_t idx = (size_t)l15 * 32 + kr * 8 + quad * 2;
                union { unsigned long long u[2]; f16x8 v; } cv;
                cv.u[0] = __hip_atomic_load(rb + idx, __ATOMIC_RELAXED,
                                            __HIP_MEMORY_SCOPE_AGENT);
                cv.u[1] = __hip_atomic_load(rb + idx + 1, __ATOMIC_RELAXED,
                                            __HIP_MEMORY_SCOPE_AGENT);
                a_rem[kr] = cv.v;
            }
            // local-half MFMAs first (remote loads in flight above them).
            // wfrag slot indices are CONSTANTS: 0..3 local, 4..7 remote.
#pragma unroll
            for (int kr = 0; kr < 4; ++kr)
#pragma unroll
                for (int t = 0; t < 4; ++t)
                    acc[t] = __builtin_amdgcn_mfma_f32_16x16x32_f16(
                        a_loc[kr], wfrag[t][kr], acc[t], 0, 0, 0);
#pragma unroll
            for (int kr = 0; kr < 4; ++kr)
#pragma unroll
                for (int t = 0; t < 4; ++t)
                    acc[t] = __builtin_amdgcn_mfma_f32_16x16x32_f16(
                        a_rem[kr], wfrag[t][4 + kr], acc[t], 0, 0, 0);
        }

        // epilogue: 4 h-values per lane (rows quad*4+r, unit u_loc).
        // C/D layout: col = l15, row = quad*4 + r.
#pragma unroll
        for (int r = 0; r < 4; ++r) {
            float gi = sig_fast (acc[0][r] + (float)tv[r][0]);
            float gf = sig_fast (acc[1][r] + (float)tv[r][1]);
            float gg = tanh_fast(acc[2][r] + (float)tv[r][2]);
            float go = sig_fast (acc[3][r] + (float)tv[r][3]);
            float cc = gf * c[r] + gi * gg;
            c[r] = cc;
            float hv = go * tanh_fast(cc);
            if (s < S_ - 1)
                hbuf[s & 1][quad * 4 + r][u_loc] = (_Float16)hv;
            else
                hlast[(row0 + r) * H_ + u_gl] = hv;   // fp32 for the head
        }

        if (s < S_ - 1) {
            __syncthreads();   // own half complete in LDS
            // repack own half -> global hx (one u64 per thread, coalesced)
            {
                const int row  = tid >> 5;        // 0..15
                const int ugrp = tid & 31;        // 0..31 (4 fp16 each)
                unsigned long long pk = *(const unsigned long long*)
                    (&hbuf[s & 1][row][ugrp * 4]);
                const size_t didx =
                    ((size_t)(self_blk * 2 + (s & 1)) * 16 + row) * 32 + ugrp;
                __hip_atomic_store(hx + didx, pk, __ATOMIC_RELAXED,
                                   __HIP_MEMORY_SCOPE_AGENT);
            }
            __syncthreads();   // all 512 stores issued before flag publish
            if (tid == 0)
                __hip_atomic_store(my_flag, s + 1, __ATOMIC_RELEASE,
                                   __HIP_MEMORY_SCOPE_AGENT);
        }
    }
}

// ---------------------------------------------------------------- K3: head
__global__ void out_kernel(const float* __restrict__ hlast,
                           const float* __restrict__ W_out,
                           const float* __restrict__ b_out,
                           float* __restrict__ out) {
    const int b = blockIdx.x;    // 256
    const int o = threadIdx.x;   // 128
    __shared__ float hl[H_];
    hl[o]       = hlast[b * H_ + o];
    hl[o + 128] = hlast[b * H_ + o + 128];
    __syncthreads();
    const float4* wp = (const float4*)(W_out + o * H_);
    float acc = 0.f;
#pragma unroll
    for (int i = 0; i < H_ / 4; ++i) {
        float4 w = wp[i];
        acc += w.x * hl[4*i] + w.y * hl[4*i+1] + w.z * hl[4*i+2] + w.w * hl[4*i+3];
    }
    out[b * O_ + o] = acc + b_out[o];
}

// ----------------------------------------------------------------- launcher
extern "C" void kernel_launch(void* const* d_in, const int* in_sizes, int n_in,
                              void* d_out, int out_size, void* d_ws, size_t ws_size,
                              hipStream_t stream) {
    const int*   x     = (const int*)  d_in[0];
    const float* emb   = (const float*)d_in[1];
    const float* W_ih  = (const float*)d_in[2];
    const float* W_hh  = (const float*)d_in[3];
    const float* b_ih  = (const float*)d_in[4];
    const float* b_hh  = (const float*)d_in[5];
    const float* W_out = (const float*)d_in[6];
    const float* b_out = (const float*)d_in[7];
    float* out = (float*)d_out;

    char* ws = (char*)d_ws;
    _Float16*           T2h   = (_Float16*)(ws + T_OFF);
    float*              hlast = (float*)(ws + HLAST_OFF);
    unsigned long long* hx    = (unsigned long long*)(ws + HX_OFF);
    int*                prog  = (int*)(ws + PROG_OFF);

    build_table<<<dim3(V_), dim3(256), 0, stream>>>(emb, W_ih, b_ih, b_hh, T2h, prog);
    lstm_persistent<<<dim3(2 * NPAIR), dim3(512), 0, stream>>>(
        x, W_hh, T2h, hx, prog, hlast);
    out_kernel<<<dim3(B_), dim3(O_), 0, stream>>>(hlast, W_out, b_out, out);
}

// Round 9
// 2248.749 us; speedup vs baseline: 2.7255x; 1.3471x over previous
//
#include <hip/hip_runtime.h>
#include <hip/hip_bf16.h>

// CharNNClassifier: out = (LSTM(emb[x]) last h) @ W_out^T + b_out
// B=256 S=512 V=256 E=128 H=256 4H=1024 O=128, fp32 in/out.
//
// R9 = R8 + cheap synchronization:
//  (1) Spin-wait polls with RELAXED agent loads; ONE acquire fence after
//      exit. (R8 polled with ACQUIRE per iteration -> agent-acquire emits an
//      L2-invalidate per poll iteration per wave -> invalidate storm; it
//      also explains R8's 38MB FETCH_SIZE = L2 refills of T2h/x each step.)
//  (2) prog flags padded to 64B apart (R8 had all 32 flags in one line).
//  (3) Local-half MFMAs hoisted BEFORE the poll (run in the wait shadow).
//
// Design recap (R8):
//  - 32 wgs x 512 threads = 16 stripe-pairs. Block q of pair p owns hidden
//    units [q*128,+128) for batch rows [p*16,+16). W_hh slice as 4x8 f16x8
//    B-frags in LOGICAL slot order (0..3 = own k-tiles, 4..7 = partner's) so
//    every wfrag index is compile-time constant (R5-R7 lesson: runtime index
//    -> SROA fails -> scratch).
//  - Exchange: own half via LDS + barrier; partner half (4 KB) via relaxed
//    AGENT-scope u64 atomics (bypass XCD L2, IF-coherent) + monotonic flags.
//  - c fp32 in regs; h rounded to fp16 once per step.

typedef _Float16 f16x8 __attribute__((ext_vector_type(8)));
typedef _Float16 f16x4 __attribute__((ext_vector_type(4)));
typedef float    f32x4 __attribute__((ext_vector_type(4)));

#define B_  256
#define S_  512
#define V_  256
#define E_  128
#define H_  256
#define O_  128
#define NPAIR 16
#define FLAG_STRIDE 16   // ints; 64B between flags

// ws layout (bytes)
#define T_OFF     0u              // T2h: 256*256*4 fp16 = 512 KiB
#define HLAST_OFF (1u << 19)      // hlast: 256 KiB
#define HX_OFF    (HLAST_OFF + (1u << 18))   // hx: 32 blocks*2*16*32 u64 = 256 KiB
#define PROG_OFF  (HX_OFF + (1u << 18))      // prog: 32*16 ints = 2 KiB

// ---------------------------------------------------------------- K1: table
// T2h[v][unit] = fp16x4 {i,f,g,o} pre-activations from the embedding path.
__global__ void build_table(const float* __restrict__ emb,
                            const float* __restrict__ W_ih,
                            const float* __restrict__ b_ih,
                            const float* __restrict__ b_hh,
                            _Float16* __restrict__ T2h,
                            int* __restrict__ prog) {
    const int v   = blockIdx.x;   // vocab id
    const int tid = threadIdx.x;  // 256 threads = hidden unit

    if (v == 0) { prog[tid] = 0; prog[tid + 256] = 0; }  // zero padded flags

    __shared__ float e[E_];
    if (tid < E_) e[tid] = emb[v * E_ + tid];
    __syncthreads();

    f16x4 tv;
#pragma unroll
    for (int t = 0; t < 4; ++t) {
        const int g = t * 256 + tid;
        const float4* wp = (const float4*)(W_ih + g * E_);
        float acc = 0.f;
#pragma unroll
        for (int i = 0; i < E_ / 4; ++i) {
            float4 w = wp[i];
            acc += w.x * e[4*i] + w.y * e[4*i+1] + w.z * e[4*i+2] + w.w * e[4*i+3];
        }
        tv[t] = (_Float16)(acc + b_ih[g] + b_hh[g]);
    }
    *(f16x4*)(T2h + ((size_t)v * 256 + tid) * 4) = tv;
}

// ------------------------------------------------------------ K2: recurrence
// clamp-free: x<<0 -> t=inf -> rcp(inf)=0 ; x>>0 -> t=0 -> 1.  NaN-free.
__device__ __forceinline__ float sig_fast(float x) {
    float t = __builtin_amdgcn_exp2f(-1.4426950408889634f * x);
    return __builtin_amdgcn_rcpf(1.f + t);
}
// abs-form: exp2 arg <= 0 -> never overflows; copysign restores sign.
__device__ __forceinline__ float tanh_fast(float x) {
    float ax = fabsf(x);
    float t  = __builtin_amdgcn_exp2f(-2.8853900817779268f * ax);  // e^{-2|x|}
    float y  = (1.f - t) * __builtin_amdgcn_rcpf(1.f + t);
    return copysignf(y, x);
}

#define HSTRIDE 136   // fp16 per LDS h row (128 + 8 pad)

__launch_bounds__(512, 1)
__global__ void lstm_persistent(const int* __restrict__ x,
                                const float* __restrict__ W_hh,
                                const _Float16* __restrict__ T2h,
                                unsigned long long* __restrict__ hx,
                                int* __restrict__ prog,
                                float* __restrict__ hlast) {
    const int tid  = threadIdx.x;
    const int wv   = tid >> 6;       // wave 0..7
    const int l    = tid & 63;
    const int l15  = l & 15;
    const int quad = l >> 4;         // 0..3
    const int pair = blockIdx.x >> 1;    // batch stripe 0..15
    const int q    = blockIdx.x & 1;     // hidden half 0..1

    // ---- prologue: W_hh slice -> fp16 B-frags in LOGICAL slot order.
    // slot 0..3 = own k-tiles (k = q*128 + slot*32); slot 4..7 = partner's.
    // Gate col for n-tile t: n = t*256 + q*128 + wv*16 + l15.
    // B[k][n] = W_hh[n][k]; lane k-offset inside a tile = quad*8 + i.
    f16x8 wfrag[4][8];
#pragma unroll
    for (int t = 0; t < 4; ++t) {
        const float* wr =
            W_hh + (size_t)(t * 256 + q * 128 + wv * 16 + l15) * H_ + quad * 8;
#pragma unroll
        for (int slot = 0; slot < 8; ++slot) {
            const int k0 = (slot < 4) ? (q * 128 + slot * 32)
                                      : ((1 - q) * 128 + (slot - 4) * 32);
            const float4* wp = (const float4*)(wr + k0);
            float4 w0 = wp[0];
            float4 w1 = wp[1];
            wfrag[t][slot] = (f16x8){
                (_Float16)w0.x, (_Float16)w0.y, (_Float16)w0.z, (_Float16)w0.w,
                (_Float16)w1.x, (_Float16)w1.y, (_Float16)w1.z, (_Float16)w1.w};
        }
    }

    // own h-half double buffer (16 rows x 128 local units)
    __shared__ __align__(16) _Float16 hbuf[2][16][HSTRIDE];

    int* my_flag = prog + (pair * 2 + q) * FLAG_STRIDE;
    const int* partner_flag = prog + (pair * 2 + (1 - q)) * FLAG_STRIDE;
    const int self_blk = pair * 2 + q;
    const int rem_blk  = pair * 2 + (1 - q);

    const int row0  = pair * 16 + quad * 4;  // this lane's 4 C-rows (global)
    const int u_loc = wv * 16 + l15;         // local unit 0..127
    const int u_gl  = q * 128 + u_loc;       // global unit

    float c[4] = {0.f, 0.f, 0.f, 0.f};

    for (int s = 0; s < S_; ++s) {
        // x indices for this lane's 4 rows (L1-resident)
        int vv[4];
#pragma unroll
        for (int r = 0; r < 4; ++r) vv[r] = x[(row0 + r) * S_ + s];
        // prefetch gate-table rows (L2) — independent of h
        f16x4 tv[4];
#pragma unroll
        for (int r = 0; r < 4; ++r)
            tv[r] = *(const f16x4*)(T2h + ((size_t)vv[r] * 256 + u_gl) * 4);

        f32x4 acc[4];
#pragma unroll
        for (int t = 0; t < 4; ++t) acc[t] = (f32x4){0.f, 0.f, 0.f, 0.f};

        if (s > 0) {
            const int par = (s - 1) & 1;
            // local A-frags from LDS: A[m=l15][k_local = kr*32 + quad*8 + i]
            const _Float16* hb = &hbuf[par][0][0] + l15 * HSTRIDE + quad * 8;
            f16x8 a_loc[4];
#pragma unroll
            for (int kr = 0; kr < 4; ++kr)
                a_loc[kr] = *(const f16x8*)(hb + kr * 32);

            // local-half MFMAs BEFORE the poll: run in the wait shadow.
#pragma unroll
            for (int kr = 0; kr < 4; ++kr)
#pragma unroll
                for (int t = 0; t < 4; ++t)
                    acc[t] = __builtin_amdgcn_mfma_f32_16x16x32_f16(
                        a_loc[kr], wfrag[t][kr], acc[t], 0, 0, 0);

            // RELAXED poll (no per-iteration L2 invalidate), then ONE
            // acquire fence to order the remote data loads below.
            while (__hip_atomic_load(partner_flag, __ATOMIC_RELAXED,
                                     __HIP_MEMORY_SCOPE_AGENT) < s) { }
            __builtin_amdgcn_fence(__ATOMIC_ACQUIRE, "agent");

            const unsigned long long* rb =
                hx + ((size_t)(rem_blk * 2 + par) * 16) * 32;
            f16x8 a_rem[4];
#pragma unroll
            for (int kr = 0; kr < 4; ++kr) {
                // A[m=l15][k_partner_local = kr*32 + quad*8 + i]
                const size_t idx = (size_t)l15 * 32 + kr * 8 + quad * 2;
                union { unsigned long long u[2]; f16x8 v; } cv;
                cv.u[0] = __hip_atomic_load(rb + idx, __ATOMIC_RELAXED,
                                            __HIP_MEMORY_SCOPE_AGENT);
                cv.u[1] = __hip_atomic_load(rb + idx + 1, __ATOMIC_RELAXED,
                                            __HIP_MEMORY_SCOPE_AGENT);
                a_rem[kr] = cv.v;
            }
#pragma unroll
            for (int kr = 0; kr < 4; ++kr)
#pragma unroll
                for (int t = 0; t < 4; ++t)
                    acc[t] = __builtin_amdgcn_mfma_f32_16x16x32_f16(
                        a_rem[kr], wfrag[t][4 + kr], acc[t], 0, 0, 0);
        }

        // epilogue: 4 h-values per lane (rows quad*4+r, unit u_loc).
        // C/D layout: col = l15, row = quad*4 + r.
#pragma unroll
        for (int r = 0; r < 4; ++r) {
            float gi = sig_fast (acc[0][r] + (float)tv[r][0]);
            float gf = sig_fast (acc[1][r] + (float)tv[r][1]);
            float gg = tanh_fast(acc[2][r] + (float)tv[r][2]);
            float go = sig_fast (acc[3][r] + (float)tv[r][3]);
            float cc = gf * c[r] + gi * gg;
            c[r] = cc;
            float hv = go * tanh_fast(cc);
            if (s < S_ - 1)
                hbuf[s & 1][quad * 4 + r][u_loc] = (_Float16)hv;
            else
                hlast[(row0 + r) * H_ + u_gl] = hv;   // fp32 for the head
        }

        if (s < S_ - 1) {
            __syncthreads();   // own half complete in LDS
            // repack own half -> global hx (one u64 per thread, coalesced)
            {
                const int row  = tid >> 5;        // 0..15
                const int ugrp = tid & 31;        // 0..31 (4 fp16 each)
                unsigned long long pk = *(const unsigned long long*)
                    (&hbuf[s & 1][row][ugrp * 4]);
                const size_t didx =
                    ((size_t)(self_blk * 2 + (s & 1)) * 16 + row) * 32 + ugrp;
                __hip_atomic_store(hx + didx, pk, __ATOMIC_RELAXED,
                                   __HIP_MEMORY_SCOPE_AGENT);
            }
            __syncthreads();   // all 512 stores ACKed (vmcnt drained) here
            if (tid == 0)
                __hip_atomic_store(my_flag, s + 1, __ATOMIC_RELEASE,
                                   __HIP_MEMORY_SCOPE_AGENT);
        }
    }
}

// ---------------------------------------------------------------- K3: head
__global__ void out_kernel(const float* __restrict__ hlast,
                           const float* __restrict__ W_out,
                           const float* __restrict__ b_out,
                           float* __restrict__ out) {
    const int b = blockIdx.x;    // 256
    const int o = threadIdx.x;   // 128
    __shared__ float hl[H_];
    hl[o]       = hlast[b * H_ + o];
    hl[o + 128] = hlast[b * H_ + o + 128];
    __syncthreads();
    const float4* wp = (const float4*)(W_out + o * H_);
    float acc = 0.f;
#pragma unroll
    for (int i = 0; i < H_ / 4; ++i) {
        float4 w = wp[i];
        acc += w.x * hl[4*i] + w.y * hl[4*i+1] + w.z * hl[4*i+2] + w.w * hl[4*i+3];
    }
    out[b * O_ + o] = acc + b_out[o];
}

// ----------------------------------------------------------------- launcher
extern "C" void kernel_launch(void* const* d_in, const int* in_sizes, int n_in,
                              void* d_out, int out_size, void* d_ws, size_t ws_size,
                              hipStream_t stream) {
    const int*   x     = (const int*)  d_in[0];
    const float* emb   = (const float*)d_in[1];
    const float* W_ih  = (const float*)d_in[2];
    const float* W_hh  = (const float*)d_in[3];
    const float* b_ih  = (const float*)d_in[4];
    const float* b_hh  = (const float*)d_in[5];
    const float* W_out = (const float*)d_in[6];
    const float* b_out = (const float*)d_in[7];
    float* out = (float*)d_out;

    char* ws = (char*)d_ws;
    _Float16*           T2h   = (_Float16*)(ws + T_OFF);
    float*              hlast = (float*)(ws + HLAST_OFF);
    unsigned long long* hx    = (unsigned long long*)(ws + HX_OFF);
    int*                prog  = (int*)(ws + PROG_OFF);

    build_table<<<dim3(V_), dim3(256), 0, stream>>>(emb, W_ih, b_ih, b_hh, T2h, prog);
    lstm_persistent<<<dim3(2 * NPAIR), dim3(512), 0, stream>>>(
        x, W_hh, T2h, hx, prog, hlast);
    out_kernel<<<dim3(B_), dim3(O_), 0, stream>>>(hlast, W_out, b_out, out);
}